// Round 5
// baseline (2691.277 us; speedup 1.0000x reference)
//
#include <hip/hip_runtime.h>
#include <stdint.h>

#define NN 20000
#define EE 320000
#define FF 64
#define ROW 128              // B*F
#define KTOP 160000
#define NEG_SLOPE 0.2f
#define LN_EPS 1e-5f
#define TCAP 65536

// ---------- precompute: rel table [4096] and wa[4][128] ----------
__global__ void precompute_kernel(const float* __restrict__ query,
                                  const float* __restrict__ rel_w,
                                  const float* __restrict__ rel_b,
                                  const float* __restrict__ W,
                                  const float* __restrict__ a,
                                  float* __restrict__ relflat,
                                  float* __restrict__ wa4) {
  int t = blockIdx.x * blockDim.x + threadIdx.x;
  if (t < 4096) {
    int bq = t >> 11, c = t & 2047;
    const float* q = query + bq * FF;
    const float* w = rel_w + (size_t)c * FF;
    float s = rel_b[c];
#pragma unroll
    for (int f = 0; f < FF; f++) s += q[f] * w[f];
    relflat[t] = s;
  }
  if (t < 512) {
    int i = t >> 7, j = t & 127;
    const float* av = a + i * FF;
    const float* w = W + (size_t)j * FF;
    float s = 0.f;
#pragma unroll
    for (int f = 0; f < FF; f++) s += w[f] * av[f];
    wa4[t] = s;
  }
}

// ---------- CSR builds (once per launch) ----------
__global__ void degcnt_kernel(const int* __restrict__ esrc, const int* __restrict__ edst,
                              unsigned int* __restrict__ deg_s, unsigned int* __restrict__ deg_d) {
  int e = blockIdx.x * blockDim.x + threadIdx.x;
  if (e < EE) {
    atomicAdd(deg_s + esrc[e], 1u);
    atomicAdd(deg_d + edst[e], 1u);
  }
}

__global__ void scan_kernel(const unsigned int* __restrict__ deg,
                            unsigned int* __restrict__ rowptr,
                            unsigned int* __restrict__ rowfill) {
  __shared__ unsigned int sh[1024];
  int t = threadIdx.x;
  const int PER = 20;  // 1024*20 >= NN
  unsigned int loc[PER];
  unsigned int sum = 0;
  int base = t * PER;
#pragma unroll
  for (int i = 0; i < PER; i++) {
    int n = base + i;
    unsigned int d = (n < NN) ? deg[n] : 0u;
    loc[i] = sum;
    sum += d;
  }
  sh[t] = sum;
  __syncthreads();
  for (int o = 1; o < 1024; o <<= 1) {
    unsigned int v = (t >= o) ? sh[t - o] : 0u;
    __syncthreads();
    sh[t] += v;
    __syncthreads();
  }
  unsigned int excl = sh[t] - sum;
#pragma unroll
  for (int i = 0; i < PER; i++) {
    int n = base + i;
    if (n < NN) {
      unsigned int rp = excl + loc[i];
      rowptr[n] = rp;
      rowfill[n] = rp;
    }
  }
  if (t == 1023) rowptr[NN] = EE;
}

// fill both CSRs; src entries packed as e | (r<<19)
__global__ void fill_kernel(const int* __restrict__ esrc, const int* __restrict__ edst,
                            const int* __restrict__ rix,
                            unsigned int* __restrict__ rowfill_s, unsigned int* __restrict__ rowfill_d,
                            unsigned int* __restrict__ cspack_s, int* __restrict__ csre_d) {
  int e = blockIdx.x * blockDim.x + threadIdx.x;
  if (e < EE) {
    unsigned int r = (unsigned int)rix[e];
    unsigned int ss = atomicAdd(rowfill_s + esrc[e], 1u);
    cspack_s[ss] = (unsigned int)e | (r << 19);
    unsigned int sd = atomicAdd(rowfill_d + edst[e], 1u);
    csre_d[sd] = e;
  }
}

// packed_d[p] = src | (r<<20) in dst-CSR order
__global__ void gatherd_kernel(const int* __restrict__ csre_d, const int* __restrict__ esrc,
                               const int* __restrict__ rix, unsigned int* __restrict__ packed_d) {
  int p = blockIdx.x * blockDim.x + threadIdx.x;
  if (p < EE) {
    int e = csre_d[p];
    packed_d[p] = (unsigned int)esrc[e] | ((unsigned int)rix[e] << 20);
  }
}

// ---------- init: racc0 and nodewa ----------
__global__ void readout_kernel(const float* __restrict__ x, float* __restrict__ racc) {
  int j = threadIdx.x;  // 0..127
  float acc = 0.f;
  for (int n = blockIdx.x; n < NN; n += gridDim.x) acc += x[(size_t)n * ROW + j];
  atomicAdd(racc + j, acc);
}

__global__ void nodewa_kernel(const float* __restrict__ x, const float* __restrict__ wa,
                              float* __restrict__ nodewa) {
  int wave = threadIdx.x >> 6, lane = threadIdx.x & 63;
  float w0 = wa[lane], w1 = wa[64 + lane];
  for (int n = blockIdx.x * 4 + wave; n < NN; n += gridDim.x * 4) {
    float s = x[(size_t)n * ROW + lane] * w0 + x[(size_t)n * ROW + 64 + lane] * w1;
#pragma unroll
    for (int off = 32; off > 0; off >>= 1) s += __shfl_xor(s, off, 64);
    if (lane == 0) nodewa[n] = s;
  }
}

// ---------- per-src softmax + alpha + 16-bit global hist ----------
// state: [0]=prefix [1]=krem [2]=T [3]=need [4]=tiecnt [5]=candCnt
__global__ __launch_bounds__(256) void alpha_csr_kernel(
    const unsigned int* __restrict__ rowptr_s, const unsigned int* __restrict__ cspack_s,
    const float* __restrict__ nodewa, const float* __restrict__ relflat,
    const float* __restrict__ wa, float* __restrict__ alpha,
    unsigned int* __restrict__ hist16, unsigned int* __restrict__ state) {
  __shared__ float relwa_sh[32];
  int t = threadIdx.x;
  if (t < 32) {
    float s = 0.f;
    const float4* rf = (const float4*)(relflat + t * ROW);
    const float4* wf = (const float4*)wa;
#pragma unroll 8
    for (int j = 0; j < 32; j++) {
      float4 r4 = rf[j], w4 = wf[j];
      s += r4.x * w4.x + r4.y * w4.y + r4.z * w4.z + r4.w * w4.w;
    }
    relwa_sh[t] = s;
  }
  if (blockIdx.x == 0 && t == 255) { state[0] = 0u; state[1] = KTOP; }
  __syncthreads();
  int n = blockIdx.x * 256 + t;
  if (n >= NN) return;
  unsigned int p0 = rowptr_s[n], p1 = rowptr_s[n + 1];
  float nw = nodewa[n];
  float denom = 0.f;
  for (unsigned int p = p0; p < p1; p++) {
    unsigned int cs = cspack_s[p];
    float v = nw + relwa_sh[cs >> 19];
    v = v > 0.f ? v : NEG_SLOPE * v;
    denom += expf(v);
  }
  float inv = 1.0f / denom;
  for (unsigned int p = p0; p < p1; p++) {
    unsigned int cs = cspack_s[p];
    float v = nw + relwa_sh[cs >> 19];
    v = v > 0.f ? v : NEG_SLOPE * v;
    float av = expf(v) * inv;
    alpha[cs & 0x7FFFFu] = av;
    atomicAdd(hist16 + (__float_as_uint(av) >> 16), 1u);
  }
}

// ---------- select over 65536 bins (1 block, 1024 threads) ----------
__global__ void sel16_kernel(unsigned int* __restrict__ state, const unsigned int* __restrict__ hist16) {
  __shared__ unsigned int sh[1024];
  int t = threadIdx.x;
  unsigned int s = 0;
  const unsigned int* hp = hist16 + t * 64;
#pragma unroll 16
  for (int i = 0; i < 64; i++) s += hp[i];
  sh[t] = s;
  __syncthreads();
  for (int o = 1; o < 1024; o <<= 1) {
    unsigned int v = (t >= o) ? sh[t - o] : 0u;
    __syncthreads();
    sh[t] += v;
    __syncthreads();
  }
  unsigned int incl = sh[t];
  unsigned int total = sh[1023];
  unsigned int krem = state[1];
  unsigned int cumAbove = total - incl;
  if (t == 0) state[5] = 0u;
  if (cumAbove < krem && cumAbove + s >= krem) {
    unsigned int cum = cumAbove;
    for (int b = 63; b >= 0; b--) {
      unsigned int c = hist16[t * 64 + b];
      if (cum + c >= krem) {
        state[0] = (unsigned int)(t * 64 + b);
        state[1] = krem - cum;
        break;
      }
      cum += c;
    }
  }
}

__global__ void select_kernel(unsigned int* __restrict__ state, unsigned int* __restrict__ hist, int shift) {
  __shared__ unsigned int sh[256];
  int t = threadIdx.x;
  sh[t] = hist[t];
  __syncthreads();
  if (t == 0) {
    unsigned int krem = state[1];
    unsigned int cum = 0;
    int bin = 255;
    for (; bin > 0; bin--) {
      unsigned int c = sh[bin];
      if (cum + c >= krem) break;
      cum += c;
    }
    unsigned int pfx = (state[0] << 8) | (unsigned)bin;
    state[0] = pfx;
    state[1] = krem - cum;
    if (shift == 0) { state[2] = pfx; state[3] = krem - cum; state[4] = 0u; }
  }
  __syncthreads();
  hist[t] = 0u;
}

__device__ __forceinline__ int wave_append(unsigned int* ctr, bool pred) {
  int lane = threadIdx.x & 63;
  unsigned long long m = __ballot(pred);
  if (m == 0ULL) return -1;
  int leader = __ffsll((unsigned long long)m) - 1;
  int base = 0;
  if (lane == leader) base = (int)atomicAdd(ctr, (unsigned int)__popcll(m));
  base = __shfl(base, leader, 64);
  if (!pred) return -1;
  unsigned long long below = m & ((1ULL << lane) - 1ULL);
  return base + (int)__popcll(below);
}

// tail pass 1: full E, match 16-bit prefix (low density) -> bits 15..8 hist + candidates
__global__ void tailB_kernel(const float* __restrict__ alpha, unsigned int* __restrict__ state,
                             unsigned int* __restrict__ hist, int* __restrict__ candA) {
  __shared__ unsigned int h[256];
  int t = threadIdx.x;
  h[t] = 0u;
  __syncthreads();
  unsigned int pfx = state[0];
  int e = blockIdx.x * 256 + t;
  bool match = false;
  unsigned int u = 0;
  if (e < EE) {
    u = __float_as_uint(alpha[e]);
    match = (u >> 16) == pfx;
  }
  if (match) atomicAdd(&h[(u >> 8) & 255u], 1u);
  int pos = wave_append(state + 5, match);
  if (match) candA[pos] = e;
  __syncthreads();
  unsigned int c = h[t];
  if (c) atomicAdd(hist + t, c);
}

// tail pass 2: over candidates, match 24-bit prefix -> bits 7..0 hist
__global__ void tailC_kernel(const float* __restrict__ alpha, const unsigned int* __restrict__ state,
                             unsigned int* __restrict__ hist, const int* __restrict__ candA) {
  __shared__ unsigned int h[256];
  int t = threadIdx.x;
  h[t] = 0u;
  __syncthreads();
  unsigned int pfx = state[0];
  unsigned int cnt = state[5];
  for (unsigned int i = blockIdx.x * 256 + t; i < cnt; i += gridDim.x * 256) {
    unsigned int u = __float_as_uint(alpha[candA[i]]);
    if ((u >> 8) == pfx) atomicAdd(&h[u & 255u], 1u);
  }
  __syncthreads();
  unsigned int c = h[t];
  if (c) atomicAdd(hist + t, c);
}

// w-select in dst-CSR order; ties appended with (e, p)
__global__ void wsel_kernel(const float* __restrict__ alpha, const int* __restrict__ csre_d,
                            unsigned int* __restrict__ state, float* __restrict__ wfin_d,
                            int* __restrict__ tie_e, int* __restrict__ tie_p) {
  int p = blockIdx.x * blockDim.x + threadIdx.x;
  if (p >= EE) return;
  int e = csre_d[p];
  float av = alpha[e];
  unsigned int u = __float_as_uint(av);
  unsigned int T = state[2];
  float w = (u > T) ? av : 0.f;
  wfin_d[p] = w;
  bool tie = (u == T);
  int pos = wave_append(state + 4, tie);
  if (tie && pos < TCAP) { tie_e[pos] = e; tie_p[pos] = p; }
}

__global__ void tiefix_kernel(const unsigned int* __restrict__ state, const int* __restrict__ tie_e,
                              const int* __restrict__ tie_p, float* __restrict__ wfin_d) {
  unsigned int need = state[3];
  unsigned int cnt = state[4];
  if (cnt > TCAP) cnt = TCAP;
  float tv = __uint_as_float(state[2]);
  for (unsigned int t = threadIdx.x; t < cnt; t += blockDim.x) {
    int e = tie_e[t];
    unsigned int rank = 0;
    for (unsigned int j = 0; j < cnt; j++) rank += (tie_e[j] < e) ? 1u : 0u;
    if (rank < need) wfin_d[tie_p[t]] = tv;
  }
}

// ---------- gather-reduce update: 4 edges x 16 lanes per wave ----------
__global__ __launch_bounds__(256) void update_kernel(const unsigned int* __restrict__ rowptr_d,
                                                     const unsigned int* __restrict__ packed_d,
                                                     const float* __restrict__ wfin_d,
                                                     const float* __restrict__ x,
                                                     const float* __restrict__ relflat,
                                                     float* __restrict__ upd,
                                                     float* __restrict__ racc_next) {
  __shared__ float relf[32 * 132];
  int t = threadIdx.x;
  if (blockIdx.x == 0 && t < 128) racc_next[t] = 0.f;
#pragma unroll
  for (int i = 0; i < 4; i++) {
    int q = t + i * 256;                 // float4 idx 0..1023
    int r = q >> 5, kq = q & 31;
    float4 v = ((const float4*)relflat)[q];
    *(float4*)(relf + r * 132 + kq * 4) = v;
  }
  __syncthreads();
  int wave = t >> 6, lane = t & 63;
  int g = lane >> 4, l = lane & 15;
  int n = blockIdx.x * 4 + wave;
  if (n >= NN) return;
  unsigned int p0 = rowptr_d[n], p1 = rowptr_d[n + 1];
  float4 A0 = {0.f, 0.f, 0.f, 0.f}, A1 = {0.f, 0.f, 0.f, 0.f};
  for (unsigned int base = p0 + g; base < p1; base += 4) {
    float w = wfin_d[base];
    if (w == 0.f) continue;
    unsigned int up = packed_d[base];
    unsigned int src = up & 0xFFFFFu;
    unsigned int r = up >> 20;
    const float* xr = x + (size_t)src * ROW + l * 8;
    const float* rr = relf + r * 132 + l * 8;
    float4 xv0 = *(const float4*)xr;
    float4 xv1 = *(const float4*)(xr + 4);
    float4 rv0 = *(const float4*)rr;
    float4 rv1 = *(const float4*)(rr + 4);
    A0.x += w * (xv0.x + rv0.x); A0.y += w * (xv0.y + rv0.y);
    A0.z += w * (xv0.z + rv0.z); A0.w += w * (xv0.w + rv0.w);
    A1.x += w * (xv1.x + rv1.x); A1.y += w * (xv1.y + rv1.y);
    A1.z += w * (xv1.z + rv1.z); A1.w += w * (xv1.w + rv1.w);
  }
#pragma unroll
  for (int off = 16; off <= 32; off <<= 1) {
    A0.x += __shfl_xor(A0.x, off, 64); A0.y += __shfl_xor(A0.y, off, 64);
    A0.z += __shfl_xor(A0.z, off, 64); A0.w += __shfl_xor(A0.w, off, 64);
    A1.x += __shfl_xor(A1.x, off, 64); A1.y += __shfl_xor(A1.y, off, 64);
    A1.z += __shfl_xor(A1.z, off, 64); A1.w += __shfl_xor(A1.w, off, 64);
  }
  if (g == 0) {
    const float* xn = x + (size_t)n * ROW + l * 8;
    float4 xs0 = *(const float4*)xn;
    float4 xs1 = *(const float4*)(xn + 4);
    float4 o0 = {A0.x + xs0.x, A0.y + xs0.y, A0.z + xs0.z, A0.w + xs0.w};
    float4 o1 = {A1.x + xs1.x, A1.y + xs1.y, A1.z + xs1.z, A1.w + xs1.w};
    float* on = upd + (size_t)n * ROW + l * 8;
    *(float4*)on = o0;
    *(float4*)(on + 4) = o1;
  }
}

// ---------- node GEMM: [64 rows x 128] @ [128 x 64] + trt + LN + ELU + residual ----------
__global__ __launch_bounds__(256) void node_gemm_kernel(const float* __restrict__ upd,
                                                        const float* __restrict__ layer_w,
                                                        const float* __restrict__ layer_b,
                                                        const float* __restrict__ racc_cur,
                                                        const float* __restrict__ tr_w,
                                                        const float* __restrict__ tr_b,
                                                        const float* __restrict__ ln_g,
                                                        const float* __restrict__ ln_b,
                                                        float* __restrict__ x,
                                                        const float* __restrict__ wa_next,
                                                        float* __restrict__ nodewa,
                                                        float* __restrict__ racc_next) {
  __shared__ float As[64 * 132];
  __shared__ float Ws[64 * 132];
  __shared__ float trt_sh[128];
  __shared__ float racc_sh[128];
  __shared__ float nodewa_sh[32];
  int t = threadIdx.x;
  int n0 = blockIdx.x * 32;
  // per-block trt (readout linear) with layer_b folded in
  if (t < 128) {
    int b = t >> 6, f = t & 63;
    const float invN = 1.0f / (float)NN;
    float s = tr_b[f] + layer_b[f];
    const float* rr = racc_cur + b * 64;
    const float* tw = tr_w + f * 64;
#pragma unroll 16
    for (int gg = 0; gg < 64; gg++) s += rr[gg] * invN * tw[gg];
    trt_sh[t] = s;
    racc_sh[t] = 0.f;
  }
  if (t < 32) nodewa_sh[t] = 0.f;
  // stage A = [x | upd] rows, stride 132
#pragma unroll
  for (int i = 0; i < 4; i++) {
    int v = t + i * 256;                  // 0..1023 float4s
    int nl = v >> 5, i4 = v & 31;
    int b = i4 >> 4, kq = i4 & 15;
    int m = nl * 2 + b;
    float4 xv = ((const float4*)x)[n0 * 32 + v];
    *(float4*)(As + m * 132 + kq * 4) = xv;
  }
#pragma unroll
  for (int i = 0; i < 4; i++) {
    int v = t + i * 256;
    int nl = v >> 5, i4 = v & 31;
    int b = i4 >> 4, kq = i4 & 15;
    int m = nl * 2 + b;
    float4 uv = ((const float4*)upd)[n0 * 32 + v];
    *(float4*)(As + m * 132 + 64 + kq * 4) = uv;
  }
  // stage W swizzled: quad q of row f at position q ^ ((f>>2)&7)
#pragma unroll
  for (int i = 0; i < 8; i++) {
    int Q = t + i * 256;                  // 0..2047
    int f = Q >> 5, q = Q & 31;
    float4 wv = ((const float4*)layer_w)[Q];
    *(float4*)(Ws + f * 132 + ((q ^ ((f >> 2) & 7)) << 2)) = wv;
  }
  __syncthreads();
  int tx = t & 15, ty = t >> 4;
  float acc[4][4] = {};
  const float* Abase = As + (ty * 4) * 132;
  const float* Wbase = Ws + (tx * 4) * 132;
  int wswz = tx & 7;
#pragma unroll 4
  for (int kq = 0; kq < 32; kq++) {
    float4 a0 = *(const float4*)(Abase + 0 * 132 + kq * 4);
    float4 a1 = *(const float4*)(Abase + 1 * 132 + kq * 4);
    float4 a2 = *(const float4*)(Abase + 2 * 132 + kq * 4);
    float4 a3 = *(const float4*)(Abase + 3 * 132 + kq * 4);
    int wq = (kq ^ wswz) << 2;
    float4 w0 = *(const float4*)(Wbase + 0 * 132 + wq);
    float4 w1 = *(const float4*)(Wbase + 1 * 132 + wq);
    float4 w2 = *(const float4*)(Wbase + 2 * 132 + wq);
    float4 w3 = *(const float4*)(Wbase + 3 * 132 + wq);
#define DOT4(A, W) (A.x * W.x + A.y * W.y + A.z * W.z + A.w * W.w)
    acc[0][0] += DOT4(a0, w0); acc[0][1] += DOT4(a0, w1); acc[0][2] += DOT4(a0, w2); acc[0][3] += DOT4(a0, w3);
    acc[1][0] += DOT4(a1, w0); acc[1][1] += DOT4(a1, w1); acc[1][2] += DOT4(a1, w2); acc[1][3] += DOT4(a1, w3);
    acc[2][0] += DOT4(a2, w0); acc[2][1] += DOT4(a2, w1); acc[2][2] += DOT4(a2, w2); acc[2][3] += DOT4(a2, w3);
    acc[3][0] += DOT4(a3, w0); acc[3][1] += DOT4(a3, w1); acc[3][2] += DOT4(a3, w2); acc[3][3] += DOT4(a3, w3);
#undef DOT4
  }
  // add trt (+layer_b); rows m = ty*4+r, b = r&1
#pragma unroll
  for (int r = 0; r < 4; r++) {
    const float* tp = trt_sh + ((r & 1) << 6) + tx * 4;
#pragma unroll
    for (int c = 0; c < 4; c++) acc[r][c] += tp[c];
  }
  // LN stats over 64 f: reduce across 16 tx lanes
  float s[4], qq[4];
#pragma unroll
  for (int r = 0; r < 4; r++) {
    s[r] = acc[r][0] + acc[r][1] + acc[r][2] + acc[r][3];
    qq[r] = acc[r][0] * acc[r][0] + acc[r][1] * acc[r][1] + acc[r][2] * acc[r][2] + acc[r][3] * acc[r][3];
  }
#pragma unroll
  for (int off = 1; off < 16; off <<= 1) {
#pragma unroll
    for (int r = 0; r < 4; r++) {
      s[r] += __shfl_xor(s[r], off, 64);
      qq[r] += __shfl_xor(qq[r], off, 64);
    }
  }
  float4 g4 = ((const float4*)ln_g)[tx];
  float4 b4 = ((const float4*)ln_b)[tx];
  float4 wn = ((const float4*)wa_next)[tx];        // b=0 cols
  float4 wn1 = ((const float4*)wa_next)[16 + tx];  // b=1 cols
  const float invF = 1.0f / (float)FF;
  float nwc[2] = {0.f, 0.f};  // per local node (ty*2, ty*2+1)
#pragma unroll
  for (int r = 0; r < 4; r++) {
    float mu = s[r] * invF;
    float var = qq[r] * invF - mu * mu;
    float rstd = 1.0f / sqrtf(var + LN_EPS);
    int m = ty * 4 + r;
    int nl = m >> 1, b = m & 1;
    // residual x from global (still old values)
    float4 xo = ((const float4*)x)[(n0 + nl) * 32 + b * 16 + tx];
    float o0 = (acc[r][0] - mu) * rstd * g4.x + b4.x;
    float o1 = (acc[r][1] - mu) * rstd * g4.y + b4.y;
    float o2 = (acc[r][2] - mu) * rstd * g4.z + b4.z;
    float o3 = (acc[r][3] - mu) * rstd * g4.w + b4.w;
    float4 y;
    y.x = (o0 > 0.f ? o0 : expm1f(o0)) + xo.x;
    y.y = (o1 > 0.f ? o1 : expm1f(o1)) + xo.y;
    y.z = (o2 > 0.f ? o2 : expm1f(o2)) + xo.z;
    y.w = (o3 > 0.f ? o3 : expm1f(o3)) + xo.w;
    ((float4*)x)[(n0 + nl) * 32 + b * 16 + tx] = y;
    // racc accumulation
    float* rs = racc_sh + (b << 6) + tx * 4;
    atomicAdd(rs + 0, y.x); atomicAdd(rs + 1, y.y);
    atomicAdd(rs + 2, y.z); atomicAdd(rs + 3, y.w);
    // nodewa contribution
    float4 w = b ? wn1 : wn;
    nwc[r >> 1] += y.x * w.x + y.y * w.y + y.z * w.z + y.w * w.w;
  }
  atomicAdd(&nodewa_sh[ty * 2 + 0], nwc[0]);
  atomicAdd(&nodewa_sh[ty * 2 + 1], nwc[1]);
  __syncthreads();
  if (t < 128) atomicAdd(racc_next + t, racc_sh[t]);
  if (t < 32) nodewa[n0 + t] = nodewa_sh[t];
}

extern "C" void kernel_launch(void* const* d_in, const int* in_sizes, int n_in,
                              void* d_out, int out_size, void* d_ws, size_t ws_size,
                              hipStream_t stream) {
  const int* ei = (const int*)d_in[0];
  const int* esrc = ei;
  const int* edst = ei + EE;
  const int* rix = (const int*)d_in[1];
  const float* boundary = (const float*)d_in[2];
  const float* query = (const float*)d_in[3];
  const float* rel_w = (const float*)d_in[4];
  const float* rel_b = (const float*)d_in[5];
  const float* layer_w = (const float*)d_in[6];
  const float* layer_b = (const float*)d_in[7];
  const float* tr_w = (const float*)d_in[8];
  const float* tr_b = (const float*)d_in[9];
  const float* Wm = (const float*)d_in[10];
  const float* av = (const float*)d_in[11];
  const float* ln_g = (const float*)d_in[12];
  const float* ln_b = (const float*)d_in[13];
  float* x = (float*)d_out;

  char* ws = (char*)d_ws;
  size_t off = 0;
  auto allocf = [&](size_t n) -> float* {
    float* p = (float*)(ws + off);
    off += ((n * 4 + 255) / 256) * 256;
    return p;
  };
  auto allocu = [&](size_t n) -> unsigned int* {
    unsigned int* p = (unsigned int*)(ws + off);
    off += ((n * 4 + 255) / 256) * 256;
    return p;
  };
  float* relflat = allocf(4096);
  float* wa4 = allocf(512);
  float* alpha = allocf(EE);
  float* wfin_d = allocf(EE);
  float* upd = allocf((size_t)NN * ROW);
  float* racc0 = allocf(128);
  float* racc1 = allocf(128);
  float* nodewa = allocf(NN);
  unsigned int* hist = allocu(256);
  unsigned int* hist16 = allocu(65536);
  unsigned int* state = allocu(8);
  unsigned int* deg_s = allocu(NN);
  unsigned int* deg_d = allocu(NN);
  unsigned int* rowptr_s = allocu(NN + 1);
  unsigned int* rowptr_d = allocu(NN + 1);
  unsigned int* rowfill_s = allocu(NN);
  unsigned int* rowfill_d = allocu(NN);
  unsigned int* cspack_s = allocu(EE);
  int* csre_d = (int*)allocu(EE);
  unsigned int* packed_d = allocu(EE);
  int* candA = (int*)allocu(EE);
  int* tie_e = (int*)allocu(TCAP);
  int* tie_p = (int*)allocu(TCAP);
  float* rbuf[2] = {racc0, racc1};

  hipMemcpyAsync(x, boundary, (size_t)NN * ROW * 4, hipMemcpyDeviceToDevice, stream);
  hipMemsetAsync(hist, 0, 256 * 4, stream);
  hipMemsetAsync(deg_s, 0, NN * 4, stream);
  hipMemsetAsync(deg_d, 0, NN * 4, stream);
  hipMemsetAsync(racc0, 0, 128 * 4, stream);
  precompute_kernel<<<16, 256, 0, stream>>>(query, rel_w, rel_b, Wm, av, relflat, wa4);

  // CSR builds (edge_index constant for this launch)
  degcnt_kernel<<<EE / 256, 256, 0, stream>>>(esrc, edst, deg_s, deg_d);
  scan_kernel<<<1, 1024, 0, stream>>>(deg_s, rowptr_s, rowfill_s);
  scan_kernel<<<1, 1024, 0, stream>>>(deg_d, rowptr_d, rowfill_d);
  fill_kernel<<<EE / 256, 256, 0, stream>>>(esrc, edst, rix, rowfill_s, rowfill_d, cspack_s, csre_d);
  gatherd_kernel<<<EE / 256, 256, 0, stream>>>(csre_d, esrc, rix, packed_d);

  // iter-0 readout sum and nodewa
  readout_kernel<<<256, 128, 0, stream>>>(x, racc0);
  nodewa_kernel<<<1250, 256, 0, stream>>>(x, wa4, nodewa);

  for (int it = 0; it < 4; it++) {
    float* rcur = rbuf[it & 1];
    float* rnxt = rbuf[(it + 1) & 1];
    const float* wa_it = wa4 + it * 128;
    const float* wa_nx = wa4 + (it < 3 ? it + 1 : 3) * 128;

    hipMemsetAsync(hist16, 0, 65536 * 4, stream);
    alpha_csr_kernel<<<(NN + 255) / 256, 256, 0, stream>>>(rowptr_s, cspack_s, nodewa,
                                                           relflat, wa_it, alpha, hist16, state);
    sel16_kernel<<<1, 1024, 0, stream>>>(state, hist16);
    tailB_kernel<<<EE / 256, 256, 0, stream>>>(alpha, state, hist, candA);
    select_kernel<<<1, 256, 0, stream>>>(state, hist, 8);
    tailC_kernel<<<64, 256, 0, stream>>>(alpha, state, hist, candA);
    select_kernel<<<1, 256, 0, stream>>>(state, hist, 0);
    wsel_kernel<<<EE / 256, 256, 0, stream>>>(alpha, csre_d, state, wfin_d, tie_e, tie_p);
    tiefix_kernel<<<1, 256, 0, stream>>>(state, tie_e, tie_p, wfin_d);

    update_kernel<<<5000, 256, 0, stream>>>(rowptr_d, packed_d, wfin_d, x, relflat, upd, rnxt);
    node_gemm_kernel<<<625, 256, 0, stream>>>(upd, layer_w, layer_b, rcur, tr_w, tr_b,
                                              ln_g, ln_b, x, wa_nx, nodewa, rnxt);
  }
}

// Round 6
// 977.832 us; speedup vs baseline: 2.7523x; 2.7523x over previous
//
#include <hip/hip_runtime.h>
#include <stdint.h>

#define NN 20000
#define EE 320000
#define FF 64
#define ROW 128              // B*F
#define KTOP 160000
#define NEG_SLOPE 0.2f
#define LN_EPS 1e-5f
#define TCAP 65536
#define H16BINS 16384        // alpha in (0,1] -> (u>>16) <= 0x3F80 < 16384

// ---------- precompute: rel table [4096] and wa[4][128] ----------
__global__ void precompute_kernel(const float* __restrict__ query,
                                  const float* __restrict__ rel_w,
                                  const float* __restrict__ rel_b,
                                  const float* __restrict__ W,
                                  const float* __restrict__ a,
                                  float* __restrict__ relflat,
                                  float* __restrict__ wa4) {
  int t = blockIdx.x * blockDim.x + threadIdx.x;
  if (t < 4096) {
    int bq = t >> 11, c = t & 2047;
    const float* q = query + bq * FF;
    const float* w = rel_w + (size_t)c * FF;
    float s = rel_b[c];
#pragma unroll
    for (int f = 0; f < FF; f++) s += q[f] * w[f];
    relflat[t] = s;
  }
  if (t < 512) {
    int i = t >> 7, j = t & 127;
    const float* av = a + i * FF;
    const float* w = W + (size_t)j * FF;
    float s = 0.f;
#pragma unroll
    for (int f = 0; f < FF; f++) s += w[f] * av[f];
    wa4[t] = s;
  }
}

// ---------- CSR builds (once per launch) ----------
__global__ void degcnt_kernel(const int* __restrict__ esrc, const int* __restrict__ edst,
                              unsigned int* __restrict__ deg_s, unsigned int* __restrict__ deg_d) {
  int e = blockIdx.x * blockDim.x + threadIdx.x;
  if (e < EE) {
    atomicAdd(deg_s + esrc[e], 1u);
    atomicAdd(deg_d + edst[e], 1u);
  }
}

__global__ void scan_kernel(const unsigned int* __restrict__ deg,
                            unsigned int* __restrict__ rowptr,
                            unsigned int* __restrict__ rowfill) {
  __shared__ unsigned int sh[1024];
  int t = threadIdx.x;
  const int PER = 20;  // 1024*20 >= NN
  unsigned int loc[PER];
  unsigned int sum = 0;
  int base = t * PER;
#pragma unroll
  for (int i = 0; i < PER; i++) {
    int n = base + i;
    unsigned int d = (n < NN) ? deg[n] : 0u;
    loc[i] = sum;
    sum += d;
  }
  sh[t] = sum;
  __syncthreads();
  for (int o = 1; o < 1024; o <<= 1) {
    unsigned int v = (t >= o) ? sh[t - o] : 0u;
    __syncthreads();
    sh[t] += v;
    __syncthreads();
  }
  unsigned int excl = sh[t] - sum;
#pragma unroll
  for (int i = 0; i < PER; i++) {
    int n = base + i;
    if (n < NN) {
      unsigned int rp = excl + loc[i];
      rowptr[n] = rp;
      rowfill[n] = rp;
    }
  }
  if (t == 1023) rowptr[NN] = EE;
}

// fill both CSRs; src entries packed as e | (r<<19)
__global__ void fill_kernel(const int* __restrict__ esrc, const int* __restrict__ edst,
                            const int* __restrict__ rix,
                            unsigned int* __restrict__ rowfill_s, unsigned int* __restrict__ rowfill_d,
                            unsigned int* __restrict__ cspack_s, int* __restrict__ csre_d) {
  int e = blockIdx.x * blockDim.x + threadIdx.x;
  if (e < EE) {
    unsigned int r = (unsigned int)rix[e];
    unsigned int ss = atomicAdd(rowfill_s + esrc[e], 1u);
    cspack_s[ss] = (unsigned int)e | (r << 19);
    unsigned int sd = atomicAdd(rowfill_d + edst[e], 1u);
    csre_d[sd] = e;
  }
}

// packed_d[p] = src | (r<<20) in dst-CSR order
__global__ void gatherd_kernel(const int* __restrict__ csre_d, const int* __restrict__ esrc,
                               const int* __restrict__ rix, unsigned int* __restrict__ packed_d) {
  int p = blockIdx.x * blockDim.x + threadIdx.x;
  if (p < EE) {
    int e = csre_d[p];
    packed_d[p] = (unsigned int)esrc[e] | ((unsigned int)rix[e] << 20);
  }
}

// ---------- init: racc0 and nodewa ----------
__global__ void readout_kernel(const float* __restrict__ x, float* __restrict__ racc) {
  int j = threadIdx.x;  // 0..127
  float acc = 0.f;
  for (int n = blockIdx.x; n < NN; n += gridDim.x) acc += x[(size_t)n * ROW + j];
  atomicAdd(racc + j, acc);
}

__global__ void nodewa_kernel(const float* __restrict__ x, const float* __restrict__ wa,
                              float* __restrict__ nodewa) {
  int wave = threadIdx.x >> 6, lane = threadIdx.x & 63;
  float w0 = wa[lane], w1 = wa[64 + lane];
  for (int n = blockIdx.x * 4 + wave; n < NN; n += gridDim.x * 4) {
    float s = x[(size_t)n * ROW + lane] * w0 + x[(size_t)n * ROW + 64 + lane] * w1;
#pragma unroll
    for (int off = 32; off > 0; off >>= 1) s += __shfl_xor(s, off, 64);
    if (lane == 0) nodewa[n] = s;
  }
}

// ---------- per-src softmax + alpha + 16-bit hist (per-block LDS, flushed once) ----------
// state: [0]=prefix [1]=krem [2]=T [3]=need [4]=tiecnt [5]=candCnt
__global__ __launch_bounds__(256) void alpha_csr_kernel(
    const unsigned int* __restrict__ rowptr_s, const unsigned int* __restrict__ cspack_s,
    const float* __restrict__ nodewa, const float* __restrict__ relflat,
    const float* __restrict__ wa, float* __restrict__ alpha,
    unsigned int* __restrict__ hist16, unsigned int* __restrict__ state) {
  __shared__ float relwa_sh[32];
  __shared__ unsigned int h16[H16BINS];  // 64 KB
  int t = threadIdx.x;
  for (int i = t; i < H16BINS; i += 256) h16[i] = 0u;
  if (t < 32) {
    float s = 0.f;
    const float4* rf = (const float4*)(relflat + t * ROW);
    const float4* wf = (const float4*)wa;
#pragma unroll 8
    for (int j = 0; j < 32; j++) {
      float4 r4 = rf[j], w4 = wf[j];
      s += r4.x * w4.x + r4.y * w4.y + r4.z * w4.z + r4.w * w4.w;
    }
    relwa_sh[t] = s;
  }
  if (blockIdx.x == 0 && t == 255) { state[0] = 0u; state[1] = KTOP; }
  __syncthreads();
  int n = blockIdx.x * 256 + t;
  if (n < NN) {
    unsigned int p0 = rowptr_s[n], p1 = rowptr_s[n + 1];
    float nw = nodewa[n];
    float denom = 0.f;
    for (unsigned int p = p0; p < p1; p++) {
      unsigned int cs = cspack_s[p];
      float v = nw + relwa_sh[cs >> 19];
      v = v > 0.f ? v : NEG_SLOPE * v;
      denom += expf(v);
    }
    float inv = 1.0f / denom;
    for (unsigned int p = p0; p < p1; p++) {
      unsigned int cs = cspack_s[p];
      float v = nw + relwa_sh[cs >> 19];
      v = v > 0.f ? v : NEG_SLOPE * v;
      float av = expf(v) * inv;
      alpha[cs & 0x7FFFFu] = av;
      unsigned int bin = __float_as_uint(av) >> 16;
      if (bin >= H16BINS) bin = H16BINS - 1;
      atomicAdd(&h16[bin], 1u);
    }
  }
  __syncthreads();
  for (int i = t; i < H16BINS; i += 256) {
    unsigned int c = h16[i];
    if (c) atomicAdd(hist16 + i, c);
  }
}

// ---------- select over 16384 bins (1 block, 1024 threads) ----------
__global__ void sel16_kernel(unsigned int* __restrict__ state, const unsigned int* __restrict__ hist16) {
  __shared__ unsigned int sh[1024];
  int t = threadIdx.x;
  unsigned int s = 0;
  const unsigned int* hp = hist16 + t * (H16BINS / 1024);
#pragma unroll
  for (int i = 0; i < H16BINS / 1024; i++) s += hp[i];
  sh[t] = s;
  __syncthreads();
  for (int o = 1; o < 1024; o <<= 1) {
    unsigned int v = (t >= o) ? sh[t - o] : 0u;
    __syncthreads();
    sh[t] += v;
    __syncthreads();
  }
  unsigned int incl = sh[t];
  unsigned int total = sh[1023];
  unsigned int krem = state[1];
  unsigned int cumAbove = total - incl;
  if (t == 0) state[5] = 0u;
  if (cumAbove < krem && cumAbove + s >= krem) {
    unsigned int cum = cumAbove;
    for (int b = H16BINS / 1024 - 1; b >= 0; b--) {
      unsigned int c = hist16[t * (H16BINS / 1024) + b];
      if (cum + c >= krem) {
        state[0] = (unsigned int)(t * (H16BINS / 1024) + b);
        state[1] = krem - cum;
        break;
      }
      cum += c;
    }
  }
}

__global__ void select_kernel(unsigned int* __restrict__ state, unsigned int* __restrict__ hist, int shift) {
  __shared__ unsigned int sh[256];
  int t = threadIdx.x;
  sh[t] = hist[t];
  __syncthreads();
  if (t == 0) {
    unsigned int krem = state[1];
    unsigned int cum = 0;
    int bin = 255;
    for (; bin > 0; bin--) {
      unsigned int c = sh[bin];
      if (cum + c >= krem) break;
      cum += c;
    }
    unsigned int pfx = (state[0] << 8) | (unsigned)bin;
    state[0] = pfx;
    state[1] = krem - cum;
    if (shift == 0) { state[2] = pfx; state[3] = krem - cum; state[4] = 0u; }
  }
  __syncthreads();
  hist[t] = 0u;
}

__device__ __forceinline__ int wave_append(unsigned int* ctr, bool pred) {
  int lane = threadIdx.x & 63;
  unsigned long long m = __ballot(pred);
  if (m == 0ULL) return -1;
  int leader = __ffsll((unsigned long long)m) - 1;
  int base = 0;
  if (lane == leader) base = (int)atomicAdd(ctr, (unsigned int)__popcll(m));
  base = __shfl(base, leader, 64);
  if (!pred) return -1;
  unsigned long long below = m & ((1ULL << lane) - 1ULL);
  return base + (int)__popcll(below);
}

// tail pass 1: full E, match 16-bit prefix (low density) -> bits 15..8 hist + candidates
__global__ void tailB_kernel(const float* __restrict__ alpha, unsigned int* __restrict__ state,
                             unsigned int* __restrict__ hist, int* __restrict__ candA) {
  __shared__ unsigned int h[256];
  int t = threadIdx.x;
  h[t] = 0u;
  __syncthreads();
  unsigned int pfx = state[0];
  int e = blockIdx.x * 256 + t;
  bool match = false;
  unsigned int u = 0;
  if (e < EE) {
    u = __float_as_uint(alpha[e]);
    match = (u >> 16) == pfx;
  }
  if (match) atomicAdd(&h[(u >> 8) & 255u], 1u);
  int pos = wave_append(state + 5, match);
  if (match) candA[pos] = e;
  __syncthreads();
  unsigned int c = h[t];
  if (c) atomicAdd(hist + t, c);
}

// tail pass 2: over candidates, match 24-bit prefix -> bits 7..0 hist
__global__ void tailC_kernel(const float* __restrict__ alpha, const unsigned int* __restrict__ state,
                             unsigned int* __restrict__ hist, const int* __restrict__ candA) {
  __shared__ unsigned int h[256];
  int t = threadIdx.x;
  h[t] = 0u;
  __syncthreads();
  unsigned int pfx = state[0];
  unsigned int cnt = state[5];
  for (unsigned int i = blockIdx.x * 256 + t; i < cnt; i += gridDim.x * 256) {
    unsigned int u = __float_as_uint(alpha[candA[i]]);
    if ((u >> 8) == pfx) atomicAdd(&h[u & 255u], 1u);
  }
  __syncthreads();
  unsigned int c = h[t];
  if (c) atomicAdd(hist + t, c);
}

// w-select in dst-CSR order; ties appended with (e, p)
__global__ void wsel_kernel(const float* __restrict__ alpha, const int* __restrict__ csre_d,
                            unsigned int* __restrict__ state, float* __restrict__ wfin_d,
                            int* __restrict__ tie_e, int* __restrict__ tie_p) {
  int p = blockIdx.x * blockDim.x + threadIdx.x;
  if (p >= EE) return;
  int e = csre_d[p];
  float av = alpha[e];
  unsigned int u = __float_as_uint(av);
  unsigned int T = state[2];
  float w = (u > T) ? av : 0.f;
  wfin_d[p] = w;
  bool tie = (u == T);
  int pos = wave_append(state + 4, tie);
  if (tie && pos < TCAP) { tie_e[pos] = e; tie_p[pos] = p; }
}

__global__ void tiefix_kernel(const unsigned int* __restrict__ state, const int* __restrict__ tie_e,
                              const int* __restrict__ tie_p, float* __restrict__ wfin_d) {
  unsigned int need = state[3];
  unsigned int cnt = state[4];
  if (cnt > TCAP) cnt = TCAP;
  float tv = __uint_as_float(state[2]);
  for (unsigned int t = threadIdx.x; t < cnt; t += blockDim.x) {
    int e = tie_e[t];
    unsigned int rank = 0;
    for (unsigned int j = 0; j < cnt; j++) rank += (tie_e[j] < e) ? 1u : 0u;
    if (rank < need) wfin_d[tie_p[t]] = tv;
  }
}

// ---------- gather-reduce update: 4 edges x 16 lanes per wave ----------
__global__ __launch_bounds__(256) void update_kernel(const unsigned int* __restrict__ rowptr_d,
                                                     const unsigned int* __restrict__ packed_d,
                                                     const float* __restrict__ wfin_d,
                                                     const float* __restrict__ x,
                                                     const float* __restrict__ relflat,
                                                     float* __restrict__ upd,
                                                     float* __restrict__ racc_next) {
  __shared__ float relf[32 * 132];
  int t = threadIdx.x;
  if (blockIdx.x == 0 && t < 128) racc_next[t] = 0.f;
#pragma unroll
  for (int i = 0; i < 4; i++) {
    int q = t + i * 256;                 // float4 idx 0..1023
    int r = q >> 5, kq = q & 31;
    float4 v = ((const float4*)relflat)[q];
    *(float4*)(relf + r * 132 + kq * 4) = v;
  }
  __syncthreads();
  int wave = t >> 6, lane = t & 63;
  int g = lane >> 4, l = lane & 15;
  int n = blockIdx.x * 4 + wave;
  if (n >= NN) return;
  unsigned int p0 = rowptr_d[n], p1 = rowptr_d[n + 1];
  float4 A0 = {0.f, 0.f, 0.f, 0.f}, A1 = {0.f, 0.f, 0.f, 0.f};
  for (unsigned int base = p0 + g; base < p1; base += 4) {
    float w = wfin_d[base];
    if (w == 0.f) continue;
    unsigned int up = packed_d[base];
    unsigned int src = up & 0xFFFFFu;
    unsigned int r = up >> 20;
    const float* xr = x + (size_t)src * ROW + l * 8;
    const float* rr = relf + r * 132 + l * 8;
    float4 xv0 = *(const float4*)xr;
    float4 xv1 = *(const float4*)(xr + 4);
    float4 rv0 = *(const float4*)rr;
    float4 rv1 = *(const float4*)(rr + 4);
    A0.x += w * (xv0.x + rv0.x); A0.y += w * (xv0.y + rv0.y);
    A0.z += w * (xv0.z + rv0.z); A0.w += w * (xv0.w + rv0.w);
    A1.x += w * (xv1.x + rv1.x); A1.y += w * (xv1.y + rv1.y);
    A1.z += w * (xv1.z + rv1.z); A1.w += w * (xv1.w + rv1.w);
  }
#pragma unroll
  for (int off = 16; off <= 32; off <<= 1) {
    A0.x += __shfl_xor(A0.x, off, 64); A0.y += __shfl_xor(A0.y, off, 64);
    A0.z += __shfl_xor(A0.z, off, 64); A0.w += __shfl_xor(A0.w, off, 64);
    A1.x += __shfl_xor(A1.x, off, 64); A1.y += __shfl_xor(A1.y, off, 64);
    A1.z += __shfl_xor(A1.z, off, 64); A1.w += __shfl_xor(A1.w, off, 64);
  }
  if (g == 0) {
    const float* xn = x + (size_t)n * ROW + l * 8;
    float4 xs0 = *(const float4*)xn;
    float4 xs1 = *(const float4*)(xn + 4);
    float4 o0 = {A0.x + xs0.x, A0.y + xs0.y, A0.z + xs0.z, A0.w + xs0.w};
    float4 o1 = {A1.x + xs1.x, A1.y + xs1.y, A1.z + xs1.z, A1.w + xs1.w};
    float* on = upd + (size_t)n * ROW + l * 8;
    *(float4*)on = o0;
    *(float4*)(on + 4) = o1;
  }
}

// ---------- node GEMM: [64 rows x 128] @ [128 x 64] + trt + LN + ELU + residual ----------
__global__ __launch_bounds__(256) void node_gemm_kernel(const float* __restrict__ upd,
                                                        const float* __restrict__ layer_w,
                                                        const float* __restrict__ layer_b,
                                                        const float* __restrict__ racc_cur,
                                                        const float* __restrict__ tr_w,
                                                        const float* __restrict__ tr_b,
                                                        const float* __restrict__ ln_g,
                                                        const float* __restrict__ ln_b,
                                                        float* __restrict__ x,
                                                        const float* __restrict__ wa_next,
                                                        float* __restrict__ nodewa,
                                                        float* __restrict__ racc_next) {
  __shared__ float As[64 * 132];
  __shared__ float Ws[64 * 132];
  __shared__ float trt_sh[128];
  __shared__ float racc_sh[128];
  __shared__ float nodewa_sh[32];
  int t = threadIdx.x;
  int n0 = blockIdx.x * 32;
  // per-block trt (readout linear) with layer_b folded in
  if (t < 128) {
    int b = t >> 6, f = t & 63;
    const float invN = 1.0f / (float)NN;
    float s = tr_b[f] + layer_b[f];
    const float* rr = racc_cur + b * 64;
    const float* tw = tr_w + f * 64;
#pragma unroll 16
    for (int gg = 0; gg < 64; gg++) s += rr[gg] * invN * tw[gg];
    trt_sh[t] = s;
    racc_sh[t] = 0.f;
  }
  if (t < 32) nodewa_sh[t] = 0.f;
  // stage A = [x | upd] rows, stride 132
#pragma unroll
  for (int i = 0; i < 4; i++) {
    int v = t + i * 256;                  // 0..1023 float4s
    int nl = v >> 5, i4 = v & 31;
    int b = i4 >> 4, kq = i4 & 15;
    int m = nl * 2 + b;
    float4 xv = ((const float4*)x)[n0 * 32 + v];
    *(float4*)(As + m * 132 + kq * 4) = xv;
  }
#pragma unroll
  for (int i = 0; i < 4; i++) {
    int v = t + i * 256;
    int nl = v >> 5, i4 = v & 31;
    int b = i4 >> 4, kq = i4 & 15;
    int m = nl * 2 + b;
    float4 uv = ((const float4*)upd)[n0 * 32 + v];
    *(float4*)(As + m * 132 + 64 + kq * 4) = uv;
  }
  // stage W swizzled: quad q of row f at position q ^ ((f>>2)&7)
#pragma unroll
  for (int i = 0; i < 8; i++) {
    int Q = t + i * 256;                  // 0..2047
    int f = Q >> 5, q = Q & 31;
    float4 wv = ((const float4*)layer_w)[Q];
    *(float4*)(Ws + f * 132 + ((q ^ ((f >> 2) & 7)) << 2)) = wv;
  }
  __syncthreads();
  int tx = t & 15, ty = t >> 4;
  float acc[4][4] = {};
  const float* Abase = As + (ty * 4) * 132;
  const float* Wbase = Ws + (tx * 4) * 132;
  int wswz = tx & 7;
#pragma unroll 4
  for (int kq = 0; kq < 32; kq++) {
    float4 a0 = *(const float4*)(Abase + 0 * 132 + kq * 4);
    float4 a1 = *(const float4*)(Abase + 1 * 132 + kq * 4);
    float4 a2 = *(const float4*)(Abase + 2 * 132 + kq * 4);
    float4 a3 = *(const float4*)(Abase + 3 * 132 + kq * 4);
    int wq = (kq ^ wswz) << 2;
    float4 w0 = *(const float4*)(Wbase + 0 * 132 + wq);
    float4 w1 = *(const float4*)(Wbase + 1 * 132 + wq);
    float4 w2 = *(const float4*)(Wbase + 2 * 132 + wq);
    float4 w3 = *(const float4*)(Wbase + 3 * 132 + wq);
#define DOT4(A, W) (A.x * W.x + A.y * W.y + A.z * W.z + A.w * W.w)
    acc[0][0] += DOT4(a0, w0); acc[0][1] += DOT4(a0, w1); acc[0][2] += DOT4(a0, w2); acc[0][3] += DOT4(a0, w3);
    acc[1][0] += DOT4(a1, w0); acc[1][1] += DOT4(a1, w1); acc[1][2] += DOT4(a1, w2); acc[1][3] += DOT4(a1, w3);
    acc[2][0] += DOT4(a2, w0); acc[2][1] += DOT4(a2, w1); acc[2][2] += DOT4(a2, w2); acc[2][3] += DOT4(a2, w3);
    acc[3][0] += DOT4(a3, w0); acc[3][1] += DOT4(a3, w1); acc[3][2] += DOT4(a3, w2); acc[3][3] += DOT4(a3, w3);
#undef DOT4
  }
  // add trt (+layer_b); rows m = ty*4+r, b = r&1
#pragma unroll
  for (int r = 0; r < 4; r++) {
    const float* tp = trt_sh + ((r & 1) << 6) + tx * 4;
#pragma unroll
    for (int c = 0; c < 4; c++) acc[r][c] += tp[c];
  }
  // LN stats over 64 f: reduce across 16 tx lanes
  float s[4], qq[4];
#pragma unroll
  for (int r = 0; r < 4; r++) {
    s[r] = acc[r][0] + acc[r][1] + acc[r][2] + acc[r][3];
    qq[r] = acc[r][0] * acc[r][0] + acc[r][1] * acc[r][1] + acc[r][2] * acc[r][2] + acc[r][3] * acc[r][3];
  }
#pragma unroll
  for (int off = 1; off < 16; off <<= 1) {
#pragma unroll
    for (int r = 0; r < 4; r++) {
      s[r] += __shfl_xor(s[r], off, 64);
      qq[r] += __shfl_xor(qq[r], off, 64);
    }
  }
  float4 g4 = ((const float4*)ln_g)[tx];
  float4 b4 = ((const float4*)ln_b)[tx];
  float4 wn = ((const float4*)wa_next)[tx];        // b=0 cols
  float4 wn1 = ((const float4*)wa_next)[16 + tx];  // b=1 cols
  const float invF = 1.0f / (float)FF;
  float nwc[2] = {0.f, 0.f};  // per local node (ty*2, ty*2+1)
#pragma unroll
  for (int r = 0; r < 4; r++) {
    float mu = s[r] * invF;
    float var = qq[r] * invF - mu * mu;
    float rstd = 1.0f / sqrtf(var + LN_EPS);
    int m = ty * 4 + r;
    int nl = m >> 1, b = m & 1;
    // residual x from global (still old values)
    float4 xo = ((const float4*)x)[(n0 + nl) * 32 + b * 16 + tx];
    float o0 = (acc[r][0] - mu) * rstd * g4.x + b4.x;
    float o1 = (acc[r][1] - mu) * rstd * g4.y + b4.y;
    float o2 = (acc[r][2] - mu) * rstd * g4.z + b4.z;
    float o3 = (acc[r][3] - mu) * rstd * g4.w + b4.w;
    float4 y;
    y.x = (o0 > 0.f ? o0 : expm1f(o0)) + xo.x;
    y.y = (o1 > 0.f ? o1 : expm1f(o1)) + xo.y;
    y.z = (o2 > 0.f ? o2 : expm1f(o2)) + xo.z;
    y.w = (o3 > 0.f ? o3 : expm1f(o3)) + xo.w;
    ((float4*)x)[(n0 + nl) * 32 + b * 16 + tx] = y;
    // racc accumulation
    float* rs = racc_sh + (b << 6) + tx * 4;
    atomicAdd(rs + 0, y.x); atomicAdd(rs + 1, y.y);
    atomicAdd(rs + 2, y.z); atomicAdd(rs + 3, y.w);
    // nodewa contribution
    float4 w = b ? wn1 : wn;
    nwc[r >> 1] += y.x * w.x + y.y * w.y + y.z * w.z + y.w * w.w;
  }
  atomicAdd(&nodewa_sh[ty * 2 + 0], nwc[0]);
  atomicAdd(&nodewa_sh[ty * 2 + 1], nwc[1]);
  __syncthreads();
  if (t < 128) atomicAdd(racc_next + t, racc_sh[t]);
  if (t < 32) nodewa[n0 + t] = nodewa_sh[t];
}

extern "C" void kernel_launch(void* const* d_in, const int* in_sizes, int n_in,
                              void* d_out, int out_size, void* d_ws, size_t ws_size,
                              hipStream_t stream) {
  const int* ei = (const int*)d_in[0];
  const int* esrc = ei;
  const int* edst = ei + EE;
  const int* rix = (const int*)d_in[1];
  const float* boundary = (const float*)d_in[2];
  const float* query = (const float*)d_in[3];
  const float* rel_w = (const float*)d_in[4];
  const float* rel_b = (const float*)d_in[5];
  const float* layer_w = (const float*)d_in[6];
  const float* layer_b = (const float*)d_in[7];
  const float* tr_w = (const float*)d_in[8];
  const float* tr_b = (const float*)d_in[9];
  const float* Wm = (const float*)d_in[10];
  const float* av = (const float*)d_in[11];
  const float* ln_g = (const float*)d_in[12];
  const float* ln_b = (const float*)d_in[13];
  float* x = (float*)d_out;

  char* ws = (char*)d_ws;
  size_t off = 0;
  auto allocf = [&](size_t n) -> float* {
    float* p = (float*)(ws + off);
    off += ((n * 4 + 255) / 256) * 256;
    return p;
  };
  auto allocu = [&](size_t n) -> unsigned int* {
    unsigned int* p = (unsigned int*)(ws + off);
    off += ((n * 4 + 255) / 256) * 256;
    return p;
  };
  float* relflat = allocf(4096);
  float* wa4 = allocf(512);
  float* alpha = allocf(EE);
  float* wfin_d = allocf(EE);
  float* upd = allocf((size_t)NN * ROW);
  float* racc0 = allocf(128);
  float* racc1 = allocf(128);
  float* nodewa = allocf(NN);
  unsigned int* hist = allocu(256);
  unsigned int* hist16 = allocu(H16BINS);
  unsigned int* state = allocu(8);
  unsigned int* deg_s = allocu(NN);
  unsigned int* deg_d = allocu(NN);
  unsigned int* rowptr_s = allocu(NN + 1);
  unsigned int* rowptr_d = allocu(NN + 1);
  unsigned int* rowfill_s = allocu(NN);
  unsigned int* rowfill_d = allocu(NN);
  unsigned int* cspack_s = allocu(EE);
  int* csre_d = (int*)allocu(EE);
  unsigned int* packed_d = allocu(EE);
  int* candA = (int*)allocu(EE);
  int* tie_e = (int*)allocu(TCAP);
  int* tie_p = (int*)allocu(TCAP);
  float* rbuf[2] = {racc0, racc1};

  hipMemcpyAsync(x, boundary, (size_t)NN * ROW * 4, hipMemcpyDeviceToDevice, stream);
  hipMemsetAsync(hist, 0, 256 * 4, stream);
  hipMemsetAsync(deg_s, 0, NN * 4, stream);
  hipMemsetAsync(deg_d, 0, NN * 4, stream);
  hipMemsetAsync(racc0, 0, 128 * 4, stream);
  precompute_kernel<<<16, 256, 0, stream>>>(query, rel_w, rel_b, Wm, av, relflat, wa4);

  // CSR builds (edge_index constant for this launch)
  degcnt_kernel<<<EE / 256, 256, 0, stream>>>(esrc, edst, deg_s, deg_d);
  scan_kernel<<<1, 1024, 0, stream>>>(deg_s, rowptr_s, rowfill_s);
  scan_kernel<<<1, 1024, 0, stream>>>(deg_d, rowptr_d, rowfill_d);
  fill_kernel<<<EE / 256, 256, 0, stream>>>(esrc, edst, rix, rowfill_s, rowfill_d, cspack_s, csre_d);
  gatherd_kernel<<<EE / 256, 256, 0, stream>>>(csre_d, esrc, rix, packed_d);

  // iter-0 readout sum and nodewa
  readout_kernel<<<256, 128, 0, stream>>>(x, racc0);
  nodewa_kernel<<<1250, 256, 0, stream>>>(x, wa4, nodewa);

  for (int it = 0; it < 4; it++) {
    float* rcur = rbuf[it & 1];
    float* rnxt = rbuf[(it + 1) & 1];
    const float* wa_it = wa4 + it * 128;
    const float* wa_nx = wa4 + (it < 3 ? it + 1 : 3) * 128;

    hipMemsetAsync(hist16, 0, H16BINS * 4, stream);
    alpha_csr_kernel<<<(NN + 255) / 256, 256, 0, stream>>>(rowptr_s, cspack_s, nodewa,
                                                           relflat, wa_it, alpha, hist16, state);
    sel16_kernel<<<1, 1024, 0, stream>>>(state, hist16);
    tailB_kernel<<<EE / 256, 256, 0, stream>>>(alpha, state, hist, candA);
    select_kernel<<<1, 256, 0, stream>>>(state, hist, 8);
    tailC_kernel<<<64, 256, 0, stream>>>(alpha, state, hist, candA);
    select_kernel<<<1, 256, 0, stream>>>(state, hist, 0);
    wsel_kernel<<<EE / 256, 256, 0, stream>>>(alpha, csre_d, state, wfin_d, tie_e, tie_p);
    tiefix_kernel<<<1, 256, 0, stream>>>(state, tie_e, tie_p, wfin_d);

    update_kernel<<<5000, 256, 0, stream>>>(rowptr_d, packed_d, wfin_d, x, relflat, upd, rnxt);
    node_gemm_kernel<<<625, 256, 0, stream>>>(upd, layer_w, layer_b, rcur, tr_w, tr_b,
                                              ln_g, ln_b, x, wa_nx, nodewa, rnxt);
  }
}